// Round 20
// baseline (44.619 us; speedup 1.0000x reference)
//
#include <hip/hip_runtime.h>
#include <hip/hip_bf16.h>

#define BN 4096
#define DD 128

// All five bf16 matrices are pre-scaled by SQS = sqrt(2*log2(e)), so the
// MFMA dot product is directly the exp2 argument: 2^(SQS^2 * dot) = e^(2*dot).
#define SQS 1.69864356f

typedef __bf16 bf16x8 __attribute__((ext_vector_type(8)));
typedef float f32x4 __attribute__((ext_vector_type(4)));

#define WAIT_VM(N) asm volatile("s_waitcnt vmcnt(" #N ")" ::: "memory")

__device__ __forceinline__ void gload_lds16(const void* g, void* l) {
    __builtin_amdgcn_global_load_lds(
        (const __attribute__((address_space(1))) void*)g,
        (__attribute__((address_space(3))) void*)l, 16, 0, 0);
}

// RAW v_exp_f32 (quarter-rate trans pipe, 1 instruction; guarded builtin
// costs ~5 extra VALU/exp -- r16 vs r17 delta was ~8us).
__device__ __forceinline__ float fast_exp2(float x) {
#if __has_builtin(__builtin_amdgcn_exp2f)
    return __builtin_amdgcn_exp2f(x);
#else
    float r;
    asm("v_exp_f32 %0, %1" : "=v"(r) : "v"(x));
    return r;
#endif
}

// ---------------- prep: f32 -> bf16 fragment-major-16 (+gather), diag dots --
// 16x16x32 fragment layout: per 16-row panel (4096 B, 256 granules of 16 B),
// granule g holds row (g&15), elems [32*(g>>6) + 8*((g>>4)&3), +8).
// A lane l of slice s then reads granule s*64 + l at lane*16 + s*1024.
__global__ __launch_bounds__(256) void prep_kernel(
    const float* __restrict__ z1, const float* __restrict__ z2,
    const float* __restrict__ attr, const int* __restrict__ uni,
    char* __restrict__ Z1f, char* __restrict__ Z2f,
    char* __restrict__ G1f, char* __restrict__ G2f, char* __restrict__ Af,
    float* __restrict__ d1, float* __restrict__ d2, float* __restrict__ d3,
    float* __restrict__ S1, float* __restrict__ S2, float* __restrict__ out)
{
    int p = blockIdx.x;        // 16-row panel 0..255
    int t = threadIdx.x;       // 0..255
    int gid = p * 256 + t;
    if (gid < 4 * BN) { S1[gid] = 0.f; S2[gid] = 0.f; }
    if (gid == 0) out[0] = 0.f;

    int r = t >> 4, q = t & 15;        // row-in-panel (16), col-eighth (8 f32)
    int grow = p * 16 + r;
    int arow = uni[grow];

    __shared__ __hip_bfloat16 lp[5][16][128];

    const float* sp[5] = { z1 + (size_t)grow * DD, z2 + (size_t)grow * DD,
                           z1 + (size_t)arow * DD, z2 + (size_t)arow * DD,
                           attr + (size_t)arow * DD };
    float v[5][8];
    #pragma unroll
    for (int m = 0; m < 5; m++) {
        const float4* s4 = (const float4*)(sp[m] + q * 8);
        #pragma unroll
        for (int i = 0; i < 2; i++) {
            float4 f = s4[i];
            v[m][4*i+0] = f.x; v[m][4*i+1] = f.y;
            v[m][4*i+2] = f.z; v[m][4*i+3] = f.w;
        }
    }
    float p1 = 0.f, p2 = 0.f, p3 = 0.f;
    #pragma unroll
    for (int e = 0; e < 8; e++) {
        p3 += v[0][e] * v[1][e];
        p1 += v[2][e] * v[4][e];
        p2 += v[3][e] * v[4][e];
    }
    #pragma unroll
    for (int m = 1; m < 16; m <<= 1) {
        p1 += __shfl_xor(p1, m);
        p2 += __shfl_xor(p2, m);
        p3 += __shfl_xor(p3, m);
    }
    if (q == 0) { d1[grow] = p1; d2[grow] = p2; d3[grow] = p3; }

    #pragma unroll
    for (int m = 0; m < 5; m++)
        #pragma unroll
        for (int e = 0; e < 8; e++)
            lp[m][r][q * 8 + e] = __float2bfloat16(v[m][e] * SQS);
    __syncthreads();

    // Write phase: thread t writes granule t of panel p for each matrix.
    char* dsts[5] = { Z1f, Z2f, G1f, G2f, Af };
    int rw = t & 15;
    int ks = 32 * (t >> 6) + 8 * ((t >> 4) & 3);
    #pragma unroll
    for (int m = 0; m < 5; m++) {
        bf16x8 val = *reinterpret_cast<const bf16x8*>(&lp[m][rw][ks]);
        *reinterpret_cast<bf16x8*>(dsts[m] + (size_t)p * 4096 + (size_t)t * 16) = val;
    }
}

// ---------------- sweep: wave-private LDS dbuf, no barriers, counted vmcnt --
// 6144 equal waves (1536 x 4-wave blocks); each wave owns 64 X-cols (4 MFMA
// chains x 16, xb in regs) and a 256-row Y-chunk = 16 x 16-row panels staged
// via global_load_lds into the wave's PRIVATE 2 x 4 KB LDS double buffer.
// No __syncthreads / s_barrier anywhere: buffers are wave-private, the only
// sync is the wave's own counted WAIT_VM(4) (panel t ready; panel t+1 stays
// in flight).  vs r19's global->reg streaming this frees 32 VGPR (footprint
// ~110 -> 4 waves/SIMD) and staging no longer blocks on register dests.
// DS-pipe cost returns at only ~7.7us total -- under the 12.4us MFMA floor.
// Swapped operands (A=Y, B=X): D[row=Y=(l>>4)*4+reg][col=X=l&15]; Y-rowsum
// = sum 4 regs/panel; tail = 2 shfl_xor + 8 atomics.  Loop ROLLED, ternary
// buffer select (rule #20 clean).  WRITE_SIZE is the spill tripwire.
__global__ __launch_bounds__(256) void sweep_kernel(
    const char* __restrict__ Z1f, const char* __restrict__ Z2f,
    const char* __restrict__ G1f, const char* __restrict__ G2f,
    const char* __restrict__ Af,
    float* __restrict__ S1, float* __restrict__ S2)
{
    int wid  = threadIdx.x >> 6;
    int gwid = blockIdx.x * 4 + wid;       // 0..6143
    int lane = threadIdx.x & 63;

    int job, xblk, ychunk;
    const char *X, *Y;
    if (gwid < 2048) {            // jobs 0/1: 64 xblk x 16 ychunk (256 rows)
        job = gwid >> 10;
        int rem = gwid & 1023;
        xblk = rem >> 4;          // 0..63
        ychunk = rem & 15;        // 0..15
        X = job ? G2f : G1f;
        Y = Af;
    } else {                      // jobs 2/3: 64 xblk x 32 ychunk (256 rows)
        int g2 = gwid - 2048;
        job = 2 + (g2 >> 11);
        int rem = g2 & 2047;
        xblk = rem >> 5;          // 0..63
        int yc = rem & 31;        // 0..31
        X = (job == 2) ? Z1f : Z2f;
        Y = (yc < 16) ? Z1f : Z2f;
        ychunk = yc & 15;
    }

    __shared__ char lds[4][2][4096];       // per-wave private double buffer
    char* l0 = &lds[wid][0][0];
    char* l1 = &lds[wid][1][0];

    size_t laneoff = (size_t)lane * 16;

    // X: 4 chains of 16 cols (B operand), in registers for the whole sweep.
    const char* xp = X + (size_t)(xblk * 4) * 4096 + laneoff;
    bf16x8 xb0[4], xb1[4], xb2[4], xb3[4];
    #pragma unroll
    for (int s = 0; s < 4; s++) {
        xb0[s] = *reinterpret_cast<const bf16x8*>(xp + s * 1024);
        xb1[s] = *reinterpret_cast<const bf16x8*>(xp + 4096 + s * 1024);
        xb2[s] = *reinterpret_cast<const bf16x8*>(xp + 8192 + s * 1024);
        xb3[s] = *reinterpret_cast<const bf16x8*>(xp + 12288 + s * 1024);
    }

    // Per-chain accumulators (X-col = xblk*64 + chain*16 + (l&15)).
    float a0e = 0.f, a0q = 0.f, a1e = 0.f, a1q = 0.f;
    float a2e = 0.f, a2q = 0.f, a3e = 0.f, a3q = 0.f;

    const char* yp = Y + (size_t)ychunk * 65536;   // 256 rows = 16 panels

    // Stage panel t (4096 B): 4 x global_load_lds, identity mapping
    // (LDS dest = uniform base + lane*16; source adds lane*16).
    auto stage = [&](char* dst, int t) {
        const char* g = yp + (size_t)t * 4096 + laneoff;
        #pragma unroll
        for (int i = 0; i < 4; i++)
            gload_lds16(g + i * 1024, dst + i * 1024);
    };

    stage(l0, 0);

    #pragma clang loop unroll(disable)
    for (int t = 0; t < 16; t++) {
        const char* cur = (t & 1) ? l1 : l0;
        char* nxt = (t & 1) ? l0 : l1;
        if (t + 1 < 16) {
            stage(nxt, t + 1);      // prefetch next panel (other buffer)
            WAIT_VM(4);             // panel t landed; t+1 stays in flight
        } else {
            WAIT_VM(0);
        }
        f32x4 c0 = {0.f,0.f,0.f,0.f}, c1 = {0.f,0.f,0.f,0.f};
        f32x4 c2 = {0.f,0.f,0.f,0.f}, c3 = {0.f,0.f,0.f,0.f};
        #pragma unroll
        for (int s = 0; s < 4; s++) {
            bf16x8 yf = *reinterpret_cast<const bf16x8*>(cur + s * 1024 + laneoff);
            c0 = __builtin_amdgcn_mfma_f32_16x16x32_bf16(yf, xb0[s], c0, 0, 0, 0);
            c1 = __builtin_amdgcn_mfma_f32_16x16x32_bf16(yf, xb1[s], c1, 0, 0, 0);
            c2 = __builtin_amdgcn_mfma_f32_16x16x32_bf16(yf, xb2[s], c2, 0, 0, 0);
            c3 = __builtin_amdgcn_mfma_f32_16x16x32_bf16(yf, xb3[s], c3, 0, 0, 0);
        }
        // inputs pre-scaled: c = (2*log2 e)*dot -> e = e^(2*dot).
        #pragma unroll
        for (int q = 0; q < 4; q++) {
            float e0 = fast_exp2(c0[q]);
            a0e += e0; a0q = fmaf(e0, e0, a0q);
            float e1 = fast_exp2(c1[q]);
            a1e += e1; a1q = fmaf(e1, e1, a1q);
            float e2 = fast_exp2(c2[q]);
            a2e += e2; a2q = fmaf(e2, e2, a2q);
            float e3 = fast_exp2(c3[q]);
            a3e += e3; a3q = fmaf(e3, e3, a3q);
        }
    }

    // Reduce the 4 lane-groups (disjoint Y-rows, same X-col) and commit.
    #pragma unroll
    for (int k = 16; k <= 32; k <<= 1) {
        a0e += __shfl_xor(a0e, k); a0q += __shfl_xor(a0q, k);
        a1e += __shfl_xor(a1e, k); a1q += __shfl_xor(a1q, k);
        a2e += __shfl_xor(a2e, k); a2q += __shfl_xor(a2q, k);
        a3e += __shfl_xor(a3e, k); a3q += __shfl_xor(a3q, k);
    }
    if (lane < 16) {
        int base = job * BN + xblk * 64 + lane;
        atomicAdd(&S1[base],      a0e); atomicAdd(&S2[base],      a0q);
        atomicAdd(&S1[base + 16], a1e); atomicAdd(&S2[base + 16], a1q);
        atomicAdd(&S1[base + 32], a2e); atomicAdd(&S2[base + 32], a2q);
        atomicAdd(&S1[base + 48], a3e); atomicAdd(&S2[base + 48], a3q);
    }
}

// ---------------- finalize: per-row loss terms -> weighted mean --------------
__global__ __launch_bounds__(256) void finalize_kernel(
    const float* __restrict__ S1, const float* __restrict__ S2,
    const float* __restrict__ d1, const float* __restrict__ d2,
    const float* __restrict__ d3, float* __restrict__ out)
{
    int idx = blockIdx.x * 256 + threadIdx.x;   // 0..16383
    float term = 0.f;
    const float EM2 = 0.13533528323661270f;     // e^-2
    if (idx < 8192) {                           // inter jobs 0/1
        int j = idx >> 12, i = idx & 4095;
        float dv = j ? d2[i] : d1[i];
        float n = 4095.f;
        float pos = __expf(2.f * dv);
        float s1 = S1[j * BN + i] - pos;
        float s2 = S2[j * BN + i] - pos * pos;
        float rw = s2 * n / s1;
        float ng = (-0.1f * n * pos + rw) * (1.f / 0.9f);
        ng = fmaxf(ng, n * EM2);
        term = logf((pos + ng) / pos) * (0.5f / 4096.f);
    } else {                                    // intra rows 0..8191
        int i = idx - 8192;
        int ii = i & 4095;
        int job = 2 + (i >> 12);
        float n = 8190.f;
        const float E2 = 7.3890560989306495f, E4 = 54.598150033144236f;
        float pos = __expf(2.f * d3[ii]);
        float s1 = S1[job * BN + ii] - E2 - pos;
        float s2 = S2[job * BN + ii] - E4 - pos * pos;
        float rw = s2 * n / s1;
        float ng = (-0.1f * n * pos + rw) * (1.f / 0.9f);
        ng = fmaxf(ng, n * EM2);
        term = logf((pos + ng) / pos) * (1.f / 8192.f);
    }

    #pragma unroll
    for (int m = 1; m < 64; m <<= 1) term += __shfl_xor(term, m);
    __shared__ float sm[4];
    int wid = threadIdx.x >> 6;
    if ((threadIdx.x & 63) == 0) sm[wid] = term;
    __syncthreads();
    if (threadIdx.x == 0) atomicAdd(out, sm[0] + sm[1] + sm[2] + sm[3]);
}

extern "C" void kernel_launch(void* const* d_in, const int* in_sizes, int n_in,
                              void* d_out, int out_size, void* d_ws, size_t ws_size,
                              hipStream_t stream)
{
    const float* z1   = (const float*)d_in[0];
    const float* z2   = (const float*)d_in[1];
    // d_in[2] = text_z : unused by the reference
    const float* attr = (const float*)d_in[3];
    const int*   uni  = (const int*)d_in[4];
    float* out = (float*)d_out;

    char* ws = (char*)d_ws;
    size_t matb = (size_t)BN * DD * 2;               // bytes per bf16 matrix
    char* Z1f = ws;
    char* Z2f = Z1f + matb;
    char* G1f = Z2f + matb;
    char* G2f = G1f + matb;
    char* Af  = G2f + matb;
    float* S1 = (float*)(ws + 5 * matb);
    float* S2 = S1 + 4 * BN;
    float* d1 = S2 + 4 * BN;
    float* d2 = d1 + BN;
    float* d3 = d2 + BN;

    prep_kernel<<<256, 256, 0, stream>>>(z1, z2, attr, uni,
                                         Z1f, Z2f, G1f, G2f, Af,
                                         d1, d2, d3, S1, S2, out);
    sweep_kernel<<<1536, 256, 0, stream>>>(Z1f, Z2f, G1f, G2f, Af, S1, S2);
    finalize_kernel<<<64, 256, 0, stream>>>(S1, S2, d1, d2, d3, out);
}

// Round 21
// 40.090 us; speedup vs baseline: 1.1130x; 1.1130x over previous
//
#include <hip/hip_runtime.h>
#include <hip/hip_bf16.h>

#define BN 4096
#define DD 128

// All five bf16 matrices are pre-scaled by SQS = sqrt(2*log2(e)), so the
// MFMA dot product is directly the exp2 argument: 2^(SQS^2 * dot) = e^(2*dot).
#define SQS 1.69864356f

typedef __bf16 bf16x8 __attribute__((ext_vector_type(8)));
typedef float f32x4 __attribute__((ext_vector_type(4)));

// RAW v_exp_f32 (quarter-rate trans pipe, 1 instruction; guarded builtin
// costs ~5 extra VALU/exp -- r16 vs r17 delta was ~8us).
__device__ __forceinline__ float fast_exp2(float x) {
#if __has_builtin(__builtin_amdgcn_exp2f)
    return __builtin_amdgcn_exp2f(x);
#else
    float r;
    asm("v_exp_f32 %0, %1" : "=v"(r) : "v"(x));
    return r;
#endif
}

// ---------------- prep: f32 -> bf16 fragment-major-16 (+gather), diag dots --
// 16x16x32 fragment layout: per 16-row panel (4096 B, 256 granules of 16 B),
// granule g holds row (g&15), elems [32*(g>>6) + 8*((g>>4)&3), +8).
// A lane l of slice s then reads granule s*64 + l at lane*16 + s*1024.
__global__ __launch_bounds__(256) void prep_kernel(
    const float* __restrict__ z1, const float* __restrict__ z2,
    const float* __restrict__ attr, const int* __restrict__ uni,
    char* __restrict__ Z1f, char* __restrict__ Z2f,
    char* __restrict__ G1f, char* __restrict__ G2f, char* __restrict__ Af,
    float* __restrict__ d1, float* __restrict__ d2, float* __restrict__ d3,
    float* __restrict__ S1, float* __restrict__ S2, float* __restrict__ out)
{
    int p = blockIdx.x;        // 16-row panel 0..255
    int t = threadIdx.x;       // 0..255
    int gid = p * 256 + t;
    if (gid < 4 * BN) { S1[gid] = 0.f; S2[gid] = 0.f; }
    if (gid == 0) out[0] = 0.f;

    int r = t >> 4, q = t & 15;        // row-in-panel (16), col-eighth (8 f32)
    int grow = p * 16 + r;
    int arow = uni[grow];

    __shared__ __hip_bfloat16 lp[5][16][128];

    const float* sp[5] = { z1 + (size_t)grow * DD, z2 + (size_t)grow * DD,
                           z1 + (size_t)arow * DD, z2 + (size_t)arow * DD,
                           attr + (size_t)arow * DD };
    float v[5][8];
    #pragma unroll
    for (int m = 0; m < 5; m++) {
        const float4* s4 = (const float4*)(sp[m] + q * 8);
        #pragma unroll
        for (int i = 0; i < 2; i++) {
            float4 f = s4[i];
            v[m][4*i+0] = f.x; v[m][4*i+1] = f.y;
            v[m][4*i+2] = f.z; v[m][4*i+3] = f.w;
        }
    }
    float p1 = 0.f, p2 = 0.f, p3 = 0.f;
    #pragma unroll
    for (int e = 0; e < 8; e++) {
        p3 += v[0][e] * v[1][e];
        p1 += v[2][e] * v[4][e];
        p2 += v[3][e] * v[4][e];
    }
    #pragma unroll
    for (int m = 1; m < 16; m <<= 1) {
        p1 += __shfl_xor(p1, m);
        p2 += __shfl_xor(p2, m);
        p3 += __shfl_xor(p3, m);
    }
    if (q == 0) { d1[grow] = p1; d2[grow] = p2; d3[grow] = p3; }

    #pragma unroll
    for (int m = 0; m < 5; m++)
        #pragma unroll
        for (int e = 0; e < 8; e++)
            lp[m][r][q * 8 + e] = __float2bfloat16(v[m][e] * SQS);
    __syncthreads();

    // Write phase: thread t writes granule t of panel p for each matrix.
    char* dsts[5] = { Z1f, Z2f, G1f, G2f, Af };
    int rw = t & 15;
    int ks = 32 * (t >> 6) + 8 * ((t >> 4) & 3);
    #pragma unroll
    for (int m = 0; m < 5; m++) {
        bf16x8 val = *reinterpret_cast<const bf16x8*>(&lp[m][rw][ks]);
        *reinterpret_cast<bf16x8*>(dsts[m] + (size_t)p * 4096 + (size_t)t * 16) = val;
    }
}

// ---------------- sweep: free-running waves, 16x16x32, triple-buffered -----
// 3072 waves (768 x 4-wave blocks), equal work: each wave owns 64 X-cols
// (4 chains x 16) and a 512-row Y-chunk = 32 x 16-row panels streamed
// global->reg (L2-resident) through NAMED buffers yA/yB/yC (triple ping-
// pong, load->use distance = 3 COMP blocks ~ 750 cy >> L2 latency ~300 --
// r19's 2-buffer distance of ~250 cy left vmcnt stalls at 2 waves/SIMD).
// Swapped operands (A=Y, B=X): D[row=Y=(l>>4)*4+reg][col=X=l&15]; Y-rowsum
// = sum the 4 regs, accumulate over panels; tail = 2 shfl_xor + 8 atomics.
// Loop unrolled by 3 with static buffer names (rule #20 clean); no guards
// (panels 0..31 exactly: 2 prologue loads, 10 x {load+comp}x3, 2 epilogue
// comps).  WRITE_SIZE is the spill tripwire.
__global__ __launch_bounds__(256) void sweep_kernel(
    const char* __restrict__ Z1f, const char* __restrict__ Z2f,
    const char* __restrict__ G1f, const char* __restrict__ G2f,
    const char* __restrict__ Af,
    float* __restrict__ S1, float* __restrict__ S2)
{
    int gwid = blockIdx.x * 4 + (threadIdx.x >> 6);   // 0..3071
    int lane = threadIdx.x & 63;

    int job, xblk, ychunk;
    const char *X, *Y;
    if (gwid < 1024) {            // jobs 0/1: 64 xblk x 8 ychunk each
        job = gwid >> 9;
        int rem = gwid & 511;
        xblk = rem >> 3;          // 0..63
        ychunk = rem & 7;         // 0..7 (512 rows each)
        X = job ? G2f : G1f;
        Y = Af;
    } else {                      // jobs 2/3: 64 xblk x 16 ychunk each
        int g2 = gwid - 1024;
        job = 2 + (g2 >> 10);
        int rem = g2 & 1023;
        xblk = rem >> 4;          // 0..63
        int yc = rem & 15;        // 0..15
        X = (job == 2) ? Z1f : Z2f;
        Y = (yc < 8) ? Z1f : Z2f;
        ychunk = yc & 7;
    }

    size_t laneoff = (size_t)lane * 16;

    // X: 4 chains of 16 cols (B operand), in registers for the whole sweep.
    const char* xp = X + (size_t)(xblk * 4) * 4096 + laneoff;
    bf16x8 xb0[4], xb1[4], xb2[4], xb3[4];
    #pragma unroll
    for (int s = 0; s < 4; s++) {
        xb0[s] = *reinterpret_cast<const bf16x8*>(xp + s * 1024);
        xb1[s] = *reinterpret_cast<const bf16x8*>(xp + 4096 + s * 1024);
        xb2[s] = *reinterpret_cast<const bf16x8*>(xp + 8192 + s * 1024);
        xb3[s] = *reinterpret_cast<const bf16x8*>(xp + 12288 + s * 1024);
    }

    // Per-chain accumulators (X-col = xblk*64 + chain*16 + (l&15)).
    float a0e = 0.f, a0q = 0.f, a1e = 0.f, a1q = 0.f;
    float a2e = 0.f, a2q = 0.f, a3e = 0.f, a3q = 0.f;

    bf16x8 yA[4], yB[4], yC[4];
    const char* yb0 = Y + (size_t)ychunk * 131072 + laneoff;   // 512 rows

#define LOADY(BUF, PTR)                                                      \
    {                                                                        \
        const char* p_ = (PTR);                                              \
        _Pragma("unroll")                                                    \
        for (int s = 0; s < 4; s++)                                          \
            BUF[s] = *reinterpret_cast<const bf16x8*>(p_ + s * 1024);        \
    }

#define COMPY(BUF)                                                           \
    {                                                                        \
        f32x4 c0 = {0.f,0.f,0.f,0.f}, c1 = {0.f,0.f,0.f,0.f};                \
        f32x4 c2 = {0.f,0.f,0.f,0.f}, c3 = {0.f,0.f,0.f,0.f};                \
        _Pragma("unroll")                                                    \
        for (int s = 0; s < 4; s++) {                                        \
            c0 = __builtin_amdgcn_mfma_f32_16x16x32_bf16(BUF[s], xb0[s], c0, 0, 0, 0); \
            c1 = __builtin_amdgcn_mfma_f32_16x16x32_bf16(BUF[s], xb1[s], c1, 0, 0, 0); \
            c2 = __builtin_amdgcn_mfma_f32_16x16x32_bf16(BUF[s], xb2[s], c2, 0, 0, 0); \
            c3 = __builtin_amdgcn_mfma_f32_16x16x32_bf16(BUF[s], xb3[s], c3, 0, 0, 0); \
        }                                                                    \
        _Pragma("unroll")                                                    \
        for (int q = 0; q < 4; q++) {                                        \
            float e0 = fast_exp2(c0[q]);                                     \
            a0e += e0; a0q = fmaf(e0, e0, a0q);                              \
            float e1 = fast_exp2(c1[q]);                                     \
            a1e += e1; a1q = fmaf(e1, e1, a1q);                              \
            float e2 = fast_exp2(c2[q]);                                     \
            a2e += e2; a2q = fmaf(e2, e2, a2q);                              \
            float e3 = fast_exp2(c3[q]);                                     \
            a3e += e3; a3q = fmaf(e3, e3, a3q);                              \
        }                                                                    \
    }

    LOADY(yA, yb0)                         // panel 0
    LOADY(yB, yb0 + 4096)                  // panel 1
    #pragma clang loop unroll(disable)
    for (int it = 0; it < 10; it++) {      // panels 3it .. 3it+2
        const char* pb = yb0 + (size_t)(3 * it) * 4096;
        LOADY(yC, pb + 2 * 4096)           // panel 3it+2
        COMPY(yA)                          // panel 3it
        LOADY(yA, pb + 3 * 4096)           // panel 3it+3
        COMPY(yB)                          // panel 3it+1
        LOADY(yB, pb + 4 * 4096)           // panel 3it+4
        COMPY(yC)                          // panel 3it+2
    }
    COMPY(yA)                              // panel 30
    COMPY(yB)                              // panel 31
#undef LOADY
#undef COMPY

    // Reduce the 4 lane-groups (disjoint Y-rows, same X-col) and commit.
    #pragma unroll
    for (int k = 16; k <= 32; k <<= 1) {
        a0e += __shfl_xor(a0e, k); a0q += __shfl_xor(a0q, k);
        a1e += __shfl_xor(a1e, k); a1q += __shfl_xor(a1q, k);
        a2e += __shfl_xor(a2e, k); a2q += __shfl_xor(a2q, k);
        a3e += __shfl_xor(a3e, k); a3q += __shfl_xor(a3q, k);
    }
    if (lane < 16) {
        int base = job * BN + xblk * 64 + lane;
        atomicAdd(&S1[base],      a0e); atomicAdd(&S2[base],      a0q);
        atomicAdd(&S1[base + 16], a1e); atomicAdd(&S2[base + 16], a1q);
        atomicAdd(&S1[base + 32], a2e); atomicAdd(&S2[base + 32], a2q);
        atomicAdd(&S1[base + 48], a3e); atomicAdd(&S2[base + 48], a3q);
    }
}

// ---------------- finalize: per-row loss terms -> weighted mean --------------
__global__ __launch_bounds__(256) void finalize_kernel(
    const float* __restrict__ S1, const float* __restrict__ S2,
    const float* __restrict__ d1, const float* __restrict__ d2,
    const float* __restrict__ d3, float* __restrict__ out)
{
    int idx = blockIdx.x * 256 + threadIdx.x;   // 0..16383
    float term = 0.f;
    const float EM2 = 0.13533528323661270f;     // e^-2
    if (idx < 8192) {                           // inter jobs 0/1
        int j = idx >> 12, i = idx & 4095;
        float dv = j ? d2[i] : d1[i];
        float n = 4095.f;
        float pos = __expf(2.f * dv);
        float s1 = S1[j * BN + i] - pos;
        float s2 = S2[j * BN + i] - pos * pos;
        float rw = s2 * n / s1;
        float ng = (-0.1f * n * pos + rw) * (1.f / 0.9f);
        ng = fmaxf(ng, n * EM2);
        term = logf((pos + ng) / pos) * (0.5f / 4096.f);
    } else {                                    // intra rows 0..8191
        int i = idx - 8192;
        int ii = i & 4095;
        int job = 2 + (i >> 12);
        float n = 8190.f;
        const float E2 = 7.3890560989306495f, E4 = 54.598150033144236f;
        float pos = __expf(2.f * d3[ii]);
        float s1 = S1[job * BN + ii] - E2 - pos;
        float s2 = S2[job * BN + ii] - E4 - pos * pos;
        float rw = s2 * n / s1;
        float ng = (-0.1f * n * pos + rw) * (1.f / 0.9f);
        ng = fmaxf(ng, n * EM2);
        term = logf((pos + ng) / pos) * (1.f / 8192.f);
    }

    #pragma unroll
    for (int m = 1; m < 64; m <<= 1) term += __shfl_xor(term, m);
    __shared__ float sm[4];
    int wid = threadIdx.x >> 6;
    if ((threadIdx.x & 63) == 0) sm[wid] = term;
    __syncthreads();
    if (threadIdx.x == 0) atomicAdd(out, sm[0] + sm[1] + sm[2] + sm[3]);
}

extern "C" void kernel_launch(void* const* d_in, const int* in_sizes, int n_in,
                              void* d_out, int out_size, void* d_ws, size_t ws_size,
                              hipStream_t stream)
{
    const float* z1   = (const float*)d_in[0];
    const float* z2   = (const float*)d_in[1];
    // d_in[2] = text_z : unused by the reference
    const float* attr = (const float*)d_in[3];
    const int*   uni  = (const int*)d_in[4];
    float* out = (float*)d_out;

    char* ws = (char*)d_ws;
    size_t matb = (size_t)BN * DD * 2;               // bytes per bf16 matrix
    char* Z1f = ws;
    char* Z2f = Z1f + matb;
    char* G1f = Z2f + matb;
    char* G2f = G1f + matb;
    char* Af  = G2f + matb;
    float* S1 = (float*)(ws + 5 * matb);
    float* S2 = S1 + 4 * BN;
    float* d1 = S2 + 4 * BN;
    float* d2 = d1 + BN;
    float* d3 = d2 + BN;

    prep_kernel<<<256, 256, 0, stream>>>(z1, z2, attr, uni,
                                         Z1f, Z2f, G1f, G2f, Af,
                                         d1, d2, d3, S1, S2, out);
    sweep_kernel<<<768, 256, 0, stream>>>(Z1f, Z2f, G1f, G2f, Af, S1, S2);
    finalize_kernel<<<64, 256, 0, stream>>>(S1, S2, d1, d2, d3, out);
}

// Round 22
// 31.304 us; speedup vs baseline: 1.4254x; 1.2807x over previous
//
#include <hip/hip_runtime.h>
#include <hip/hip_bf16.h>

#define BN 4096
#define DD 128

// All five fp8 matrices are pre-scaled by SQS = sqrt(2*log2(e)), so the
// MFMA dot product is directly the exp2 argument: 2^(SQS^2 * dot) = e^(2*dot).
#define SQS 1.69864356f

typedef float f32x4 __attribute__((ext_vector_type(4)));
typedef int   i32x8 __attribute__((ext_vector_type(8)));
typedef int   i32x2 __attribute__((ext_vector_type(2)));

// RAW v_exp_f32 (quarter-rate trans pipe, 1 instruction; guarded builtin
// costs ~5 extra VALU/exp -- r16 vs r17 delta was ~8us).
__device__ __forceinline__ float fast_exp2(float x) {
#if __has_builtin(__builtin_amdgcn_exp2f)
    return __builtin_amdgcn_exp2f(x);
#else
    float r;
    asm("v_exp_f32 %0, %1" : "=v"(r) : "v"(x));
    return r;
#endif
}

// ---------------- prep: f32 -> fp8 e4m3 fragment-major (+gather), diag dots -
// fp8 K=128 fragment layout (self-consistent bijection): per 16-row panel
// (2048 B), lane l's 32 bytes at l*32 hold row (l&15), k = 32*(l>>4)+[0..32).
// Any k-bijection is correct as long as X and Y use the SAME one (MFMA
// reduces over all slots), and our Y-rowsum makes the D row-order moot;
// only D col = lane&15 matters (verified dtype/shape-independent).
__global__ __launch_bounds__(256) void prep_kernel(
    const float* __restrict__ z1, const float* __restrict__ z2,
    const float* __restrict__ attr, const int* __restrict__ uni,
    char* __restrict__ Z1f, char* __restrict__ Z2f,
    char* __restrict__ G1f, char* __restrict__ G2f, char* __restrict__ Af,
    float* __restrict__ d1, float* __restrict__ d2, float* __restrict__ d3,
    float* __restrict__ S1, float* __restrict__ S2, float* __restrict__ out)
{
    int p = blockIdx.x;        // 16-row panel 0..255
    int t = threadIdx.x;       // 0..255
    int gid = p * 256 + t;
    if (gid < 4 * BN) { S1[gid] = 0.f; S2[gid] = 0.f; }
    if (gid == 0) out[0] = 0.f;

    int r = t >> 4, q = t & 15;        // row-in-panel (16), col-eighth (8 f32)
    int grow = p * 16 + r;
    int arow = uni[grow];

    __shared__ float lp[5][16][128];   // SQS-prescaled f32 staging (40 KB)

    const float* sp[5] = { z1 + (size_t)grow * DD, z2 + (size_t)grow * DD,
                           z1 + (size_t)arow * DD, z2 + (size_t)arow * DD,
                           attr + (size_t)arow * DD };
    float v[5][8];
    #pragma unroll
    for (int m = 0; m < 5; m++) {
        const float4* s4 = (const float4*)(sp[m] + q * 8);
        #pragma unroll
        for (int i = 0; i < 2; i++) {
            float4 f = s4[i];
            v[m][4*i+0] = f.x; v[m][4*i+1] = f.y;
            v[m][4*i+2] = f.z; v[m][4*i+3] = f.w;
        }
    }
    float p1 = 0.f, p2 = 0.f, p3 = 0.f;   // diag dots stay f32-exact
    #pragma unroll
    for (int e = 0; e < 8; e++) {
        p3 += v[0][e] * v[1][e];
        p1 += v[2][e] * v[4][e];
        p2 += v[3][e] * v[4][e];
    }
    #pragma unroll
    for (int m = 1; m < 16; m <<= 1) {
        p1 += __shfl_xor(p1, m);
        p2 += __shfl_xor(p2, m);
        p3 += __shfl_xor(p3, m);
    }
    if (q == 0) { d1[grow] = p1; d2[grow] = p2; d3[grow] = p3; }

    #pragma unroll
    for (int m = 0; m < 5; m++)
        #pragma unroll
        for (int e = 0; e < 8; e++)
            lp[m][r][q * 8 + e] = v[m][e] * SQS;
    __syncthreads();

    // Write phase: thread t writes fragment bytes [t*8, t*8+8) of panel p:
    // slot l = t>>2 -> row (t>>2)&15, k0 = 32*(t>>6) + (t&3)*8.
    char* dsts[5] = { Z1f, Z2f, G1f, G2f, Af };
    int rw = (t >> 2) & 15;
    int k0 = 32 * (t >> 6) + (t & 3) * 8;
    #pragma unroll
    for (int m = 0; m < 5; m++) {
        const float* s = &lp[m][rw][k0];
        int w0 = __builtin_amdgcn_cvt_pk_fp8_f32(s[0], s[1], 0, false);
        w0     = __builtin_amdgcn_cvt_pk_fp8_f32(s[2], s[3], w0, true);
        int w1 = __builtin_amdgcn_cvt_pk_fp8_f32(s[4], s[5], 0, false);
        w1     = __builtin_amdgcn_cvt_pk_fp8_f32(s[6], s[7], w1, true);
        i32x2 w = { w0, w1 };
        *reinterpret_cast<i32x2*>(dsts[m] + (size_t)p * 2048 + (size_t)t * 8) = w;
    }
}

// ---------------- sweep: free-running waves, fp8-MX K=128, triple-buffered -
// 3072 waves (768 x 4-wave blocks), equal work: each wave owns 64 X-cols
// (4 chains x 16, xb 32 regs fp8) and a 512-row Y-chunk = 32 x 16-row fp8
// panels (2048 B each) streamed global->reg through yA/yB/yC (8 regs each).
// mfma_scale_f32_16x16x128_f8f6f4 with unit scales (0x7F7F7F7F: every E8M0
// byte = 2^0, immune to opsel byte-select semantics) consumes K=128 in ONE
// instruction -> 4 MFMA/panel (vs 16 bf16) and MFMA floor 12.4 -> 5.5us.
// Footprint ~92 regs -> 4 waves/SIMD (vs 2 at r21's ~150) -- the residency
// that r17-r21 showed was the real limiter.  Y traffic halves (fp8).
// Swapped operands (A=Y, B=X): D col = lane&15 = X-col; all 16 D-rows are
// summed so the D row-order and the k-bijection are correctness-irrelevant.
// WRITE_SIZE is the spill tripwire.
__global__ __launch_bounds__(256) void sweep_kernel(
    const char* __restrict__ Z1f, const char* __restrict__ Z2f,
    const char* __restrict__ G1f, const char* __restrict__ G2f,
    const char* __restrict__ Af,
    float* __restrict__ S1, float* __restrict__ S2)
{
    int gwid = blockIdx.x * 4 + (threadIdx.x >> 6);   // 0..3071
    int lane = threadIdx.x & 63;

    int job, xblk, ychunk;
    const char *X, *Y;
    if (gwid < 1024) {            // jobs 0/1: 64 xblk x 8 ychunk each
        job = gwid >> 9;
        int rem = gwid & 511;
        xblk = rem >> 3;          // 0..63
        ychunk = rem & 7;         // 0..7 (512 rows each)
        X = job ? G2f : G1f;
        Y = Af;
    } else {                      // jobs 2/3: 64 xblk x 16 ychunk each
        int g2 = gwid - 1024;
        job = 2 + (g2 >> 10);
        int rem = g2 & 1023;
        xblk = rem >> 4;          // 0..63
        int yc = rem & 15;        // 0..15
        X = (job == 2) ? Z1f : Z2f;
        Y = (yc < 8) ? Z1f : Z2f;
        ychunk = yc & 7;
    }

    size_t laneoff = (size_t)lane * 32;

    // X: 4 chains of 16 cols (B operand), 8 regs each, resident all sweep.
    const char* xp = X + (size_t)(xblk * 4) * 2048 + laneoff;
    i32x8 xb0 = *reinterpret_cast<const i32x8*>(xp);
    i32x8 xb1 = *reinterpret_cast<const i32x8*>(xp + 2048);
    i32x8 xb2 = *reinterpret_cast<const i32x8*>(xp + 4096);
    i32x8 xb3 = *reinterpret_cast<const i32x8*>(xp + 6144);

    // Per-chain accumulators (X-col = xblk*64 + chain*16 + (l&15)).
    float a0e = 0.f, a0q = 0.f, a1e = 0.f, a1q = 0.f;
    float a2e = 0.f, a2q = 0.f, a3e = 0.f, a3q = 0.f;

    i32x8 yA, yB, yC;
    const char* yb0 = Y + (size_t)ychunk * 65536 + laneoff;   // 512 rows

#define LOADY(BUF, PTR) BUF = *reinterpret_cast<const i32x8*>(PTR);

#define COMPY(BUF)                                                           \
    {                                                                        \
        f32x4 c0 = {0.f,0.f,0.f,0.f}, c1 = {0.f,0.f,0.f,0.f};                \
        f32x4 c2 = {0.f,0.f,0.f,0.f}, c3 = {0.f,0.f,0.f,0.f};                \
        c0 = __builtin_amdgcn_mfma_scale_f32_16x16x128_f8f6f4(               \
                 BUF, xb0, c0, 0, 0, 0, 0x7F7F7F7F, 0, 0x7F7F7F7F);          \
        c1 = __builtin_amdgcn_mfma_scale_f32_16x16x128_f8f6f4(               \
                 BUF, xb1, c1, 0, 0, 0, 0x7F7F7F7F, 0, 0x7F7F7F7F);          \
        c2 = __builtin_amdgcn_mfma_scale_f32_16x16x128_f8f6f4(               \
                 BUF, xb2, c2, 0, 0, 0, 0x7F7F7F7F, 0, 0x7F7F7F7F);          \
        c3 = __builtin_amdgcn_mfma_scale_f32_16x16x128_f8f6f4(               \
                 BUF, xb3, c3, 0, 0, 0, 0x7F7F7F7F, 0, 0x7F7F7F7F);          \
        _Pragma("unroll")                                                    \
        for (int q = 0; q < 4; q++) {                                        \
            float e0 = fast_exp2(c0[q]);                                     \
            a0e += e0; a0q = fmaf(e0, e0, a0q);                              \
            float e1 = fast_exp2(c1[q]);                                     \
            a1e += e1; a1q = fmaf(e1, e1, a1q);                              \
            float e2 = fast_exp2(c2[q]);                                     \
            a2e += e2; a2q = fmaf(e2, e2, a2q);                              \
            float e3 = fast_exp2(c3[q]);                                     \
            a3e += e3; a3q = fmaf(e3, e3, a3q);                              \
        }                                                                    \
    }

    LOADY(yA, yb0)                         // panel 0
    LOADY(yB, yb0 + 2048)                  // panel 1
    #pragma clang loop unroll(disable)
    for (int it = 0; it < 10; it++) {      // panels 3it .. 3it+2
        const char* pb = yb0 + (size_t)(3 * it) * 2048;
        LOADY(yC, pb + 2 * 2048)           // panel 3it+2
        COMPY(yA)                          // panel 3it
        LOADY(yA, pb + 3 * 2048)           // panel 3it+3
        COMPY(yB)                          // panel 3it+1
        LOADY(yB, pb + 4 * 2048)           // panel 3it+4
        COMPY(yC)                          // panel 3it+2
    }
    COMPY(yA)                              // panel 30
    COMPY(yB)                              // panel 31
#undef LOADY
#undef COMPY

    // Reduce the 4 lane-groups (disjoint Y-rows, same X-col) and commit.
    #pragma unroll
    for (int k = 16; k <= 32; k <<= 1) {
        a0e += __shfl_xor(a0e, k); a0q += __shfl_xor(a0q, k);
        a1e += __shfl_xor(a1e, k); a1q += __shfl_xor(a1q, k);
        a2e += __shfl_xor(a2e, k); a2q += __shfl_xor(a2q, k);
        a3e += __shfl_xor(a3e, k); a3q += __shfl_xor(a3q, k);
    }
    if (lane < 16) {
        int base = job * BN + xblk * 64 + lane;
        atomicAdd(&S1[base],      a0e); atomicAdd(&S2[base],      a0q);
        atomicAdd(&S1[base + 16], a1e); atomicAdd(&S2[base + 16], a1q);
        atomicAdd(&S1[base + 32], a2e); atomicAdd(&S2[base + 32], a2q);
        atomicAdd(&S1[base + 48], a3e); atomicAdd(&S2[base + 48], a3q);
    }
}

// ---------------- finalize: per-row loss terms -> weighted mean --------------
__global__ __launch_bounds__(256) void finalize_kernel(
    const float* __restrict__ S1, const float* __restrict__ S2,
    const float* __restrict__ d1, const float* __restrict__ d2,
    const float* __restrict__ d3, float* __restrict__ out)
{
    int idx = blockIdx.x * 256 + threadIdx.x;   // 0..16383
    float term = 0.f;
    const float EM2 = 0.13533528323661270f;     // e^-2
    if (idx < 8192) {                           // inter jobs 0/1
        int j = idx >> 12, i = idx & 4095;
        float dv = j ? d2[i] : d1[i];
        float n = 4095.f;
        float pos = __expf(2.f * dv);
        float s1 = S1[j * BN + i] - pos;
        float s2 = S2[j * BN + i] - pos * pos;
        float rw = s2 * n / s1;
        float ng = (-0.1f * n * pos + rw) * (1.f / 0.9f);
        ng = fmaxf(ng, n * EM2);
        term = logf((pos + ng) / pos) * (0.5f / 4096.f);
    } else {                                    // intra rows 0..8191
        int i = idx - 8192;
        int ii = i & 4095;
        int job = 2 + (i >> 12);
        float n = 8190.f;
        const float E2 = 7.3890560989306495f, E4 = 54.598150033144236f;
        float pos = __expf(2.f * d3[ii]);
        float s1 = S1[job * BN + ii] - E2 - pos;
        float s2 = S2[job * BN + ii] - E4 - pos * pos;
        float rw = s2 * n / s1;
        float ng = (-0.1f * n * pos + rw) * (1.f / 0.9f);
        ng = fmaxf(ng, n * EM2);
        term = logf((pos + ng) / pos) * (1.f / 8192.f);
    }

    #pragma unroll
    for (int m = 1; m < 64; m <<= 1) term += __shfl_xor(term, m);
    __shared__ float sm[4];
    int wid = threadIdx.x >> 6;
    if ((threadIdx.x & 63) == 0) sm[wid] = term;
    __syncthreads();
    if (threadIdx.x == 0) atomicAdd(out, sm[0] + sm[1] + sm[2] + sm[3]);
}

extern "C" void kernel_launch(void* const* d_in, const int* in_sizes, int n_in,
                              void* d_out, int out_size, void* d_ws, size_t ws_size,
                              hipStream_t stream)
{
    const float* z1   = (const float*)d_in[0];
    const float* z2   = (const float*)d_in[1];
    // d_in[2] = text_z : unused by the reference
    const float* attr = (const float*)d_in[3];
    const int*   uni  = (const int*)d_in[4];
    float* out = (float*)d_out;

    char* ws = (char*)d_ws;
    size_t matb = (size_t)BN * DD;                   // bytes per fp8 matrix
    char* Z1f = ws;
    char* Z2f = Z1f + matb;
    char* G1f = Z2f + matb;
    char* G2f = G1f + matb;
    char* Af  = G2f + matb;
    float* S1 = (float*)(ws + 5 * matb);
    float* S2 = S1 + 4 * BN;
    float* d1 = S2 + 4 * BN;
    float* d2 = d1 + BN;
    float* d3 = d2 + BN;

    prep_kernel<<<256, 256, 0, stream>>>(z1, z2, attr, uni,
                                         Z1f, Z2f, G1f, G2f, Af,
                                         d1, d2, d3, S1, S2, out);
    sweep_kernel<<<768, 256, 0, stream>>>(Z1f, Z2f, G1f, G2f, Af, S1, S2);
    finalize_kernel<<<64, 256, 0, stream>>>(S1, S2, d1, d2, d3, out);
}